// Round 2
// baseline (72.940 us; speedup 1.0000x reference)
//
#include <hip/hip_runtime.h>

// XORNet SNN: x(T,B,2) -> spikes(T,B,2), Leaky(beta=0.9, thr=1, subtract-reset)
// Each batch element independent: thread holds membrane state in registers,
// walks T sequentially. 2 elements/thread => float4 (16B/lane) loads/stores.
// Streaming roofline: 2 x 167.8 MB @ ~6.3 TB/s => ~53 us floor.

constexpr int   T    = 20;
constexpr float BETA = 0.9f;
constexpr float THR  = 1.0f;

__global__ __launch_bounds__(256) void snn_xornet_kernel(
    const float* __restrict__ x,
    const float* __restrict__ W1,   // (4,2) row-major
    const float* __restrict__ W2,   // (2,4) row-major
    float* __restrict__ out,
    int nPairs)                     // B/2
{
    const int tid = blockIdx.x * blockDim.x + threadIdx.x;
    if (tid >= nPairs) return;

    // Weights: wave-uniform addresses -> scalar loads; 16 floats, one-time.
    float w1[4][2], w2[2][4];
    #pragma unroll
    for (int o = 0; o < 4; ++o) {
        w1[o][0] = W1[o * 2 + 0];
        w1[o][1] = W1[o * 2 + 1];
    }
    #pragma unroll
    for (int o = 0; o < 2; ++o)
        #pragma unroll
        for (int i = 0; i < 4; ++i)
            w2[o][i] = W2[o * 4 + i];

    // Per-element state (2 batch elements per thread), all register-resident
    // (every index below is compile-time constant after unrolling).
    float m1[2][4] = {}, s1[2][4] = {};
    float m2[2][2] = {}, s2[2][2] = {};

    const float4* __restrict__ xp = reinterpret_cast<const float4*>(x) + tid;
    float4* __restrict__       op = reinterpret_cast<float4*>(out) + tid;
    const size_t strideT = (size_t)nPairs;  // one t-slice in float4 units

    #pragma unroll
    for (int t = 0; t < T; ++t) {
        const float4 xv = xp[t * strideT];
        const float xin[2][2] = {{xv.x, xv.y}, {xv.z, xv.w}};
        float so[2][2];

        #pragma unroll
        for (int e = 0; e < 2; ++e) {
            // layer 1: cur1 = x @ W1^T ; leaky integrate + subtract reset
            #pragma unroll
            for (int o = 0; o < 4; ++o) {
                const float cur1 = xin[e][0] * w1[o][0] + xin[e][1] * w1[o][1];
                m1[e][o] = BETA * m1[e][o] + cur1 - s1[e][o] * THR;
                s1[e][o] = (m1[e][o] > THR) ? 1.0f : 0.0f;
            }
            // layer 2: cur2 = s1 @ W2^T
            #pragma unroll
            for (int o = 0; o < 2; ++o) {
                float cur2 = s1[e][0] * w2[o][0];
                #pragma unroll
                for (int i = 1; i < 4; ++i) cur2 += s1[e][i] * w2[o][i];
                m2[e][o] = BETA * m2[e][o] + cur2 - s2[e][o] * THR;
                s2[e][o] = (m2[e][o] > THR) ? 1.0f : 0.0f;
                so[e][o] = s2[e][o];
            }
        }

        float4 ov;
        ov.x = so[0][0]; ov.y = so[0][1];
        ov.z = so[1][0]; ov.w = so[1][1];
        op[t * strideT] = ov;
    }
}

extern "C" void kernel_launch(void* const* d_in, const int* in_sizes, int n_in,
                              void* d_out, int out_size, void* d_ws, size_t ws_size,
                              hipStream_t stream) {
    const float* x  = (const float*)d_in[0];
    const float* W1 = (const float*)d_in[1];
    const float* W2 = (const float*)d_in[2];
    float* out = (float*)d_out;

    const int B = in_sizes[0] / (T * 2);   // x is (T,B,2)
    const int nPairs = B / 2;              // 2 batch elements per thread

    const int block = 256;
    const int grid  = (nPairs + block - 1) / block;
    snn_xornet_kernel<<<grid, block, 0, stream>>>(x, W1, W2, out, nPairs);
}

// Round 4
// 50.650 us; speedup vs baseline: 1.4401x; 1.4401x over previous
//
#include <hip/hip_runtime.h>

// XORNet SNN: x(T,B,2) -> spikes(T,B,2), Leaky(beta=0.9, thr=1, subtract-reset)
// Each batch element independent: thread holds membrane state in registers,
// walks T sequentially. 2 elements/thread => 16B/lane loads/stores.
//
// R2 finding: FETCH=84MB = exactly half of x -> out's write stream evicts x
// from the 256MB L3 across graph replays (168+168 > 256). Output has zero
// cache reuse -> non-temporal stores keep x fully L3-resident.
// R3: use clang ext_vector_type for the nt-store builtin (HIP float4 is a
// class, rejected by __builtin_nontemporal_store).

constexpr int   T    = 20;
constexpr float BETA = 0.9f;
constexpr float THR  = 1.0f;

typedef float f32x4 __attribute__((ext_vector_type(4)));

__global__ __launch_bounds__(256) void snn_xornet_kernel(
    const float* __restrict__ x,
    const float* __restrict__ W1,   // (4,2) row-major
    const float* __restrict__ W2,   // (2,4) row-major
    float* __restrict__ out,
    int nPairs)                     // B/2
{
    const int tid = blockIdx.x * blockDim.x + threadIdx.x;
    if (tid >= nPairs) return;

    // Weights: wave-uniform addresses -> scalar loads; 16 floats, one-time.
    float w1[4][2], w2[2][4];
    #pragma unroll
    for (int o = 0; o < 4; ++o) {
        w1[o][0] = W1[o * 2 + 0];
        w1[o][1] = W1[o * 2 + 1];
    }
    #pragma unroll
    for (int o = 0; o < 2; ++o)
        #pragma unroll
        for (int i = 0; i < 4; ++i)
            w2[o][i] = W2[o * 4 + i];

    // Per-element state (2 batch elements per thread), all register-resident
    // (every index below is compile-time constant after unrolling).
    float m1[2][4] = {}, s1[2][4] = {};
    float m2[2][2] = {}, s2[2][2] = {};

    const f32x4* __restrict__ xp = reinterpret_cast<const f32x4*>(x) + tid;
    f32x4* __restrict__       op = reinterpret_cast<f32x4*>(out) + tid;
    const size_t strideT = (size_t)nPairs;  // one t-slice in f32x4 units

    #pragma unroll
    for (int t = 0; t < T; ++t) {
        const f32x4 xv = xp[t * strideT];
        const float xin[2][2] = {{xv.x, xv.y}, {xv.z, xv.w}};
        float so[2][2];

        #pragma unroll
        for (int e = 0; e < 2; ++e) {
            // layer 1: cur1 = x @ W1^T ; leaky integrate + subtract reset
            #pragma unroll
            for (int o = 0; o < 4; ++o) {
                const float cur1 = xin[e][0] * w1[o][0] + xin[e][1] * w1[o][1];
                m1[e][o] = BETA * m1[e][o] + cur1 - s1[e][o] * THR;
                s1[e][o] = (m1[e][o] > THR) ? 1.0f : 0.0f;
            }
            // layer 2: cur2 = s1 @ W2^T
            #pragma unroll
            for (int o = 0; o < 2; ++o) {
                float cur2 = s1[e][0] * w2[o][0];
                #pragma unroll
                for (int i = 1; i < 4; ++i) cur2 += s1[e][i] * w2[o][i];
                m2[e][o] = BETA * m2[e][o] + cur2 - s2[e][o] * THR;
                s2[e][o] = (m2[e][o] > THR) ? 1.0f : 0.0f;
                so[e][o] = s2[e][o];
            }
        }

        f32x4 ov;
        ov.x = so[0][0]; ov.y = so[0][1];
        ov.z = so[1][0]; ov.w = so[1][1];
        // Non-temporal: out is write-once, never read -> don't let it evict x
        // from L2/L3 (emits global_store_dwordx4 ... nt).
        __builtin_nontemporal_store(ov, &op[t * strideT]);
    }
}

extern "C" void kernel_launch(void* const* d_in, const int* in_sizes, int n_in,
                              void* d_out, int out_size, void* d_ws, size_t ws_size,
                              hipStream_t stream) {
    const float* x  = (const float*)d_in[0];
    const float* W1 = (const float*)d_in[1];
    const float* W2 = (const float*)d_in[2];
    float* out = (float*)d_out;

    const int B = in_sizes[0] / (T * 2);   // x is (T,B,2)
    const int nPairs = B / 2;              // 2 batch elements per thread

    const int block = 256;
    const int grid  = (nPairs + block - 1) / block;
    snn_xornet_kernel<<<grid, block, 0, stream>>>(x, W1, W2, out, nPairs);
}